// Round 9
// baseline (876.435 us; speedup 1.0000x reference)
//
#include <hip/hip_runtime.h>
#include <hip/hip_bf16.h>
#include <cstdint>
#include <cstddef>

#define TTOK   4096
#define DIM_   2048
#define INTER_ 1408
#define NEXP   16
#define SINTER_ 2816
#define BM 128
#define BN 128
#define BK 32
#define MAXROWS (TTOK*2 + NEXP*BM)      /* 10240 padded routed slots */
#define MAXMT   (TTOK*2/BM + NEXP)      /* 80 worst-case M tiles */

typedef unsigned short u16;
typedef __attribute__((ext_vector_type(8))) short short8;
typedef __attribute__((ext_vector_type(4))) float f32x4;

#define AS3P(p) ((__attribute__((address_space(3))) void*)(p))
#define AS1P(p) ((const __attribute__((address_space(1))) void*)(p))

__device__ __forceinline__ void gll16(const void* g, void* l) {
    __builtin_amdgcn_global_load_lds(AS1P(g), AS3P(l), 16, 0, 0);
}

__device__ __forceinline__ u16 f2bf(float f) {
    __hip_bfloat16 h = __float2bfloat16(f);
    union { __hip_bfloat16 h; u16 u; } c; c.h = h; return c.u;
}

__device__ __forceinline__ float bf2f(u16 u) {
    return __uint_as_float((unsigned)u << 16);
}

__device__ __forceinline__ unsigned pk2(float a, float b) {
    unsigned r;
    asm("v_cvt_pk_bf16_f32 %0, %1, %2" : "=v"(r) : "v"(a), "v"(b));
    return r;
}

__device__ __forceinline__ int4 pack8(float4 a, float4 b) {
    int4 r;
    r.x = (int)pk2(a.x, a.y);
    r.y = (int)pk2(a.z, a.w);
    r.z = (int)pk2(b.x, b.y);
    r.w = (int)pk2(b.z, b.w);
    return r;
}

// ---------------- small kernels ----------------

// misc layout (ints): [0..16) counts, [16..32) fill, [32..48) base,
//                     [48..128) tile_expert, [128..208) tile_row0
__global__ void init_kernel(int* perm_rt, float* pw_rt, int* misc, int* zrow) {
    int i = blockIdx.x * 256 + threadIdx.x;
    if (i < MAXROWS) { perm_rt[i] = -1; pw_rt[i] = 0.f; }
    if (i < 32)      misc[i] = 0;
    if (i < 1024)    zrow[i] = 0;      // 4 KB zero page
}

// f32 -> bf16, 8 elems/thread, grid-stride
__global__ void cvt_kernel(const float* __restrict__ s, u16* __restrict__ d, int n8) {
    int stride = gridDim.x * 256;
    for (int i = blockIdx.x * 256 + threadIdx.x; i < n8; i += stride) {
        const float4* s4 = (const float4*)(s + (size_t)i * 8);
        float4 a = s4[0], b = s4[1];
        *(int4*)(d + (size_t)i * 8) = pack8(a, b);
    }
}

__global__ void gate_kernel(const float* __restrict__ x, const float* __restrict__ gw,
                            int* __restrict__ topi, float* __restrict__ topw,
                            int* __restrict__ misc) {
    int t = blockIdx.x;
    int lane = threadIdx.x;
    const float* xr = x + (size_t)t * DIM_;
    float acc[NEXP];
#pragma unroll
    for (int e = 0; e < NEXP; e++) acc[e] = 0.f;
#pragma unroll
    for (int i = 0; i < 8; i++) {
        int k = i * 256 + lane * 4;
        float4 xv = *(const float4*)(xr + k);
#pragma unroll
        for (int e = 0; e < NEXP; e++) {
            float4 gv = *(const float4*)(gw + (size_t)e * DIM_ + k);
            acc[e] += xv.x * gv.x + xv.y * gv.y + xv.z * gv.z + xv.w * gv.w;
        }
    }
#pragma unroll
    for (int e = 0; e < NEXP; e++) {
        float v = acc[e];
        for (int off = 32; off > 0; off >>= 1) v += __shfl_down(v, off);
        acc[e] = v;
    }
    if (lane == 0) {
        float m = acc[0];
#pragma unroll
        for (int e = 1; e < NEXP; e++) m = fmaxf(m, acc[e]);
        float p[NEXP]; float s = 0.f;
#pragma unroll
        for (int e = 0; e < NEXP; e++) { p[e] = __expf(acc[e] - m); s += p[e]; }
        int i0 = 0; float v0 = p[0];
#pragma unroll
        for (int e = 1; e < NEXP; e++) if (p[e] > v0) { v0 = p[e]; i0 = e; }
        int i1 = -1; float v1 = -1.f;
#pragma unroll
        for (int e = 0; e < NEXP; e++) if (e != i0 && p[e] > v1) { v1 = p[e]; i1 = e; }
        float inv = 1.f / s;
        topi[2 * t] = i0; topi[2 * t + 1] = i1;
        topw[2 * t] = v0 * inv; topw[2 * t + 1] = v1 * inv;
        atomicAdd(&misc[i0], 1);
        atomicAdd(&misc[i1], 1);
    }
}

__global__ void scan_kernel(int* misc) {
    int* counts = misc;
    int* base   = misc + 32;
    int* te     = misc + 48;
    int* tr     = misc + 128;
    int b = 0, tt = 0;
    for (int e = 0; e < NEXP; e++) {
        int c = counts[e];
        int nt = (c + BM - 1) >> 7;
        base[e] = b;
        for (int i = 0; i < nt; i++) { te[tt] = e; tr[tt] = b + i * BM; tt++; }
        b += nt * BM;
    }
    for (int i = tt; i < MAXMT; i++) te[i] = -1;
}

__global__ void scatter_kernel(const int* __restrict__ topi, const float* __restrict__ topw,
                               int* __restrict__ misc, int* __restrict__ perm,
                               float* __restrict__ pw) {
    int t = blockIdx.x * 256 + threadIdx.x;
    if (t >= TTOK) return;
    int* fill = misc + 16;
    int* base = misc + 32;
#pragma unroll
    for (int k = 0; k < 2; k++) {
        int e = topi[2 * t + k];
        int pos = base[e] + atomicAdd(&fill[e], 1);
        perm[pos] = t;
        pw[pos] = topw[2 * t + k];
    }
}

// ---------------- unified single-B GEMM ----------------
// C[M,N] = A[M,K] @ B[N,K]^T, all bf16, gll16 staging, scheme-B XOR swizzle
// (R8-verified: 0 bank conflicts). Single accumulator (64 VGPR) so
// __launch_bounds__(256,3) holds without spill -> 12 waves/CU (R8 post-mortem:
// latency-bound at 8 waves/CU; occupancy is the lever).
// EPI: 0 = store silu(acc) bf16        (h1 pass)
//      1 = store bf2f(T1)*acc bf16     (h3+mul pass)
//      2 = store acc f32               (shared out; initializes d_out)
//      3 = atomicAdd(acc*pw) scatter   (routed out)
// GROUPED: expert-tile table + (EPI<2: gather A rows via perm, -1 -> zrow).
// XCD-chunked jn-major 1D grid (T1).
// NOTE: dual-acc variant at (256,4) spilled catastrophically (R5); single-acc
// at (256,3) is ~120 regs vs cap 170 — safe.

template<bool GROUPED, int EPI>
__global__ __launch_bounds__(256, 3) void gemm_s(
    const u16* __restrict__ A, const u16* __restrict__ B,
    const u16* __restrict__ T1, u16* __restrict__ OutB, float* __restrict__ OutF,
    const int* __restrict__ perm, const float* __restrict__ pw,
    const int* __restrict__ te, const int* __restrict__ tr,
    const u16* __restrict__ zrow,
    int N, int K, int nt_m, int chunk)
{
    const int q = (blockIdx.x & 7) * chunk + (blockIdx.x >> 3);
    if (q >= nt_m * (N / BN)) return;
    const int jn = q / nt_m, im = q % nt_m;
    int e, slot0;
    if (GROUPED) { e = te[im]; if (e < 0) return; slot0 = tr[im]; }
    else         { e = 0; slot0 = im * BM; }
    const int n0 = jn * BN;
    const u16* Bw = B + (size_t)e * N * K;

    __shared__ __align__(16) u16 As[BM * BK];
    __shared__ __align__(16) u16 Bs[BM * BK];

    const int tid = threadIdx.x;
    const int lane = tid & 63, wid = tid >> 6;
    const int wr = wid >> 1, wc = wid & 1;
    const int col = lane & 15, kg = lane >> 4;

    // staging: lane l -> row l>>2, pre-swizzled global chunk (l&3)^((l>>3)&3)
    const int lr = lane >> 2;
    const int kb = ((lane & 3) ^ ((lane >> 3) & 3)) * 8;   // u16 elems
    const int ar0 = wid * 32 + lr, ar1 = ar0 + 16;
    const u16* ga0;
    const u16* ga1;
    if (GROUPED && EPI < 2) {
        const int ta0 = perm[slot0 + ar0];
        const int ta1 = perm[slot0 + ar1];
        ga0 = (ta0 >= 0 ? A + (size_t)ta0 * K : zrow) + kb;
        ga1 = (ta1 >= 0 ? A + (size_t)ta1 * K : zrow) + kb;
    } else {
        ga0 = A + (size_t)(slot0 + ar0) * K + kb;
        ga1 = A + (size_t)(slot0 + ar1) * K + kb;
    }
    const u16* gb0 = Bw + (size_t)(n0 + ar0) * K + kb;
    const u16* gb1 = Bw + (size_t)(n0 + ar1) * K + kb;
    u16* la0 = As + (wid * 32) * BK;        // wave-uniform; HW adds lane*16B
    u16* la1 = As + (wid * 32 + 16) * BK;
    u16* lb0 = Bs + (wid * 32) * BK;
    u16* lb1 = Bs + (wid * 32 + 16) * BK;

    const int sw = (col >> 1) & 3;           // read-side swizzle key

    f32x4 acc[4][4] = {};

    for (int k0 = 0; k0 < K; k0 += BK) {
        gll16(ga0 + k0, la0);
        gll16(ga1 + k0, la1);
        gll16(gb0 + k0, lb0);
        gll16(gb1 + k0, lb1);
        __syncthreads();

        short8 a[4];
#pragma unroll
        for (int mi = 0; mi < 4; mi++)
            a[mi] = *(const short8*)(As + (wr * 64 + mi * 16 + col) * BK + ((kg ^ sw) * 8));
#pragma unroll
        for (int ni = 0; ni < 4; ni++) {
            short8 bv = *(const short8*)(Bs + (wc * 64 + ni * 16 + col) * BK + ((kg ^ sw) * 8));
#pragma unroll
            for (int mi = 0; mi < 4; mi++)
                acc[mi][ni] = __builtin_amdgcn_mfma_f32_16x16x32_bf16(a[mi], bv, acc[mi][ni], 0, 0, 0);
        }
        __syncthreads();
    }

#pragma unroll
    for (int mi = 0; mi < 4; mi++) {
#pragma unroll
        for (int j = 0; j < 4; j++) {
            int rloc = wr * 64 + mi * 16 + kg * 4 + j;
            int slot = slot0 + rloc;
            if (EPI == 0) {
#pragma unroll
                for (int ni = 0; ni < 4; ni++) {
                    float v = acc[mi][ni][j];
                    float s = v / (1.f + __expf(-v));
                    int c = n0 + wc * 64 + ni * 16 + col;
                    OutB[(size_t)slot * N + c] = f2bf(s);
                }
            } else if (EPI == 1) {
#pragma unroll
                for (int ni = 0; ni < 4; ni++) {
                    int c = n0 + wc * 64 + ni * 16 + col;
                    float s1 = bf2f(T1[(size_t)slot * N + c]);
                    OutB[(size_t)slot * N + c] = f2bf(s1 * acc[mi][ni][j]);
                }
            } else if (EPI == 2) {
#pragma unroll
                for (int ni = 0; ni < 4; ni++) {
                    int c = n0 + wc * 64 + ni * 16 + col;
                    OutF[(size_t)slot * DIM_ + c] = acc[mi][ni][j];
                }
            } else {
                int token = perm[slot];
                if (token < 0) continue;
                float w = pw[slot];
#pragma unroll
                for (int ni = 0; ni < 4; ni++) {
                    int c = n0 + wc * 64 + ni * 16 + col;
                    atomicAdd(&OutF[(size_t)token * DIM_ + c], acc[mi][ni][j] * w);
                }
            }
        }
    }
}

// ---------------- launch ----------------

extern "C" void kernel_launch(void* const* d_in, const int* in_sizes, int n_in,
                              void* d_out, int out_size, void* d_ws, size_t ws_size,
                              hipStream_t stream) {
    (void)in_sizes; (void)n_in; (void)out_size; (void)ws_size;
    const float* x   = (const float*)d_in[0];
    const float* gw  = (const float*)d_in[1];
    const float* w1  = (const float*)d_in[2];
    const float* w2  = (const float*)d_in[3];
    const float* w3  = (const float*)d_in[4];
    const float* sw1 = (const float*)d_in[5];
    const float* sw2 = (const float*)d_in[6];
    const float* sw3 = (const float*)d_in[7];
    float* out = (float*)d_out;

    char* ws = (char*)d_ws;
    size_t off = 0;
    auto take = [&](size_t bytes) -> void* {
        void* p = ws + off;
        off += (bytes + 255) & ~(size_t)255;
        return p;
    };
    const size_t nT1 = (size_t)MAXROWS * INTER_;         // >= TTOK*SINTER_? no:
    // t1/h buffers sized for max(routed 10240*1408, shared 4096*2816) = 14.42M
    const size_t nHB = (nT1 > (size_t)TTOK * SINTER_) ? nT1 : (size_t)TTOK * SINTER_;
    u16*   xb      = (u16*)take((size_t)TTOK * DIM_ * 2);
    u16*   t1buf   = (u16*)take(nHB * 2);
    u16*   hbuf    = (u16*)take(nHB * 2);
    int*   perm_rt = (int*)take((size_t)MAXROWS * 4);
    float* pw_rt   = (float*)take((size_t)MAXROWS * 4);
    int*   topi    = (int*)take((size_t)TTOK * 2 * 4);
    float* topw    = (float*)take((size_t)TTOK * 2 * 4);
    int*   misc    = (int*)take(1024);
    int*   zrow    = (int*)take(4096);
    const size_t nW  = (size_t)NEXP * INTER_ * DIM_;     // w1 / w2 / w3 each
    const size_t nSW = (size_t)SINTER_ * DIM_;           // sw1 / sw2 / sw3 each
    u16* w1b  = (u16*)take(nW * 2);
    u16* w2b  = (u16*)take(nW * 2);
    u16* w3b  = (u16*)take(nW * 2);
    u16* sw1b = (u16*)take(nSW * 2);
    u16* sw2b = (u16*)take(nSW * 2);
    u16* sw3b = (u16*)take(nSW * 2);

    init_kernel<<<MAXROWS / 256, 256, 0, stream>>>(perm_rt, pw_rt, misc, zrow);
    cvt_kernel<<<2048, 256, 0, stream>>>(x, xb, TTOK * DIM_ / 8);
    gate_kernel<<<TTOK, 64, 0, stream>>>(x, gw, topi, topw, misc);
    scan_kernel<<<1, 1, 0, stream>>>(misc);
    scatter_kernel<<<TTOK / 256, 256, 0, stream>>>(topi, topw, misc, perm_rt, pw_rt);

    // weight conversion passes (HBM-bound)
    cvt_kernel<<<4096, 256, 0, stream>>>(w1,  w1b,  (int)(nW / 8));
    cvt_kernel<<<4096, 256, 0, stream>>>(w2,  w2b,  (int)(nW / 8));
    cvt_kernel<<<4096, 256, 0, stream>>>(w3,  w3b,  (int)(nW / 8));
    cvt_kernel<<<4096, 256, 0, stream>>>(sw1, sw1b, (int)(nSW / 8));
    cvt_kernel<<<4096, 256, 0, stream>>>(sw2, sw2b, (int)(nSW / 8));
    cvt_kernel<<<4096, 256, 0, stream>>>(sw3, sw3b, (int)(nSW / 8));

    auto grid8 = [](int total) { return ((total + 7) / 8) * 8; };
    auto chunk8 = [](int total) { return (total + 7) / 8; };

    const int ntm_sh = TTOK / BM;   // 32

    // shared expert: t1 = silu(x@sw1^T); h = t1 * (x@sw3^T); out = h@sw2^T
    {
        int total = ntm_sh * (SINTER_ / BN);
        gemm_s<false, 0><<<grid8(total), 256, 0, stream>>>(
            xb, sw1b, nullptr, t1buf, nullptr, nullptr, nullptr, nullptr, nullptr,
            (const u16*)zrow, SINTER_, DIM_, ntm_sh, chunk8(total));
        gemm_s<false, 1><<<grid8(total), 256, 0, stream>>>(
            xb, sw3b, t1buf, hbuf, nullptr, nullptr, nullptr, nullptr, nullptr,
            (const u16*)zrow, SINTER_, DIM_, ntm_sh, chunk8(total));
    }
    {
        int total = ntm_sh * (DIM_ / BN);
        gemm_s<false, 2><<<grid8(total), 256, 0, stream>>>(
            hbuf, sw2b, nullptr, nullptr, out, nullptr, nullptr, nullptr, nullptr,
            (const u16*)zrow, DIM_, SINTER_, ntm_sh, chunk8(total));
    }
    // routed experts
    {
        int total = MAXMT * (INTER_ / BN);
        gemm_s<true, 0><<<grid8(total), 256, 0, stream>>>(
            xb, w1b, nullptr, t1buf, nullptr, perm_rt, nullptr, misc + 48, misc + 128,
            (const u16*)zrow, INTER_, DIM_, MAXMT, chunk8(total));
        gemm_s<true, 1><<<grid8(total), 256, 0, stream>>>(
            xb, w3b, t1buf, hbuf, nullptr, perm_rt, nullptr, misc + 48, misc + 128,
            (const u16*)zrow, INTER_, DIM_, MAXMT, chunk8(total));
    }
    {
        int total = MAXMT * (DIM_ / BN);
        gemm_s<true, 3><<<grid8(total), 256, 0, stream>>>(
            hbuf, w2b, nullptr, nullptr, out, perm_rt, pw_rt, misc + 48, misc + 128,
            (const u16*)zrow, DIM_, INTER_, MAXMT, chunk8(total));
    }
}

// Round 10
// 798.272 us; speedup vs baseline: 1.0979x; 1.0979x over previous
//
#include <hip/hip_runtime.h>
#include <hip/hip_bf16.h>
#include <cstdint>
#include <cstddef>

#define TTOK   4096
#define DIM_   2048
#define INTER_ 1408
#define NEXP   16
#define SINTER_ 2816
#define BM 128
#define BN 128
#define BK 64
#define MAXROWS (TTOK*2 + NEXP*BM)      /* 10240 padded routed slots */
#define MAXMT   (TTOK*2/BM + NEXP)      /* 80 worst-case M tiles */

typedef unsigned short u16;
typedef __attribute__((ext_vector_type(8))) short short8;
typedef __attribute__((ext_vector_type(4))) float f32x4;

#define AS3P(p) ((__attribute__((address_space(3))) void*)(p))
#define AS1P(p) ((const __attribute__((address_space(1))) void*)(p))

__device__ __forceinline__ void gll16(const void* g, void* l) {
    __builtin_amdgcn_global_load_lds(AS1P(g), AS3P(l), 16, 0, 0);
}

__device__ __forceinline__ u16 f2bf(float f) {
    __hip_bfloat16 h = __float2bfloat16(f);
    union { __hip_bfloat16 h; u16 u; } c; c.h = h; return c.u;
}

__device__ __forceinline__ unsigned pk2(float a, float b) {
    unsigned r;
    asm("v_cvt_pk_bf16_f32 %0, %1, %2" : "=v"(r) : "v"(a), "v"(b));
    return r;
}

__device__ __forceinline__ int4 pack8(float4 a, float4 b) {
    int4 r;
    r.x = (int)pk2(a.x, a.y);
    r.y = (int)pk2(a.z, a.w);
    r.z = (int)pk2(b.x, b.y);
    r.w = (int)pk2(b.z, b.w);
    return r;
}

// ---------------- small kernels ----------------

// misc layout (ints): [0..16) counts, [16..32) fill, [32..48) base,
//                     [48..128) tile_expert, [128..208) tile_row0
__global__ void init_kernel(int* perm_rt, float* pw_rt, int* misc, int* zrow) {
    int i = blockIdx.x * 256 + threadIdx.x;
    if (i < MAXROWS) { perm_rt[i] = -1; pw_rt[i] = 0.f; }
    if (i < 32)      misc[i] = 0;
    if (i < 1024)    zrow[i] = 0;      // 4 KB zero page (= one 2048-elem bf16 row)
}

// f32 -> bf16, 8 elems/thread, grid-stride
__global__ void cvt_kernel(const float* __restrict__ s, u16* __restrict__ d, int n8) {
    int stride = gridDim.x * 256;
    for (int i = blockIdx.x * 256 + threadIdx.x; i < n8; i += stride) {
        const float4* s4 = (const float4*)(s + (size_t)i * 8);
        float4 a = s4[0], b = s4[1];
        *(int4*)(d + (size_t)i * 8) = pack8(a, b);
    }
}

__global__ void gate_kernel(const float* __restrict__ x, const float* __restrict__ gw,
                            int* __restrict__ topi, float* __restrict__ topw,
                            int* __restrict__ misc) {
    int t = blockIdx.x;
    int lane = threadIdx.x;
    const float* xr = x + (size_t)t * DIM_;
    float acc[NEXP];
#pragma unroll
    for (int e = 0; e < NEXP; e++) acc[e] = 0.f;
#pragma unroll
    for (int i = 0; i < 8; i++) {
        int k = i * 256 + lane * 4;
        float4 xv = *(const float4*)(xr + k);
#pragma unroll
        for (int e = 0; e < NEXP; e++) {
            float4 gv = *(const float4*)(gw + (size_t)e * DIM_ + k);
            acc[e] += xv.x * gv.x + xv.y * gv.y + xv.z * gv.z + xv.w * gv.w;
        }
    }
#pragma unroll
    for (int e = 0; e < NEXP; e++) {
        float v = acc[e];
        for (int off = 32; off > 0; off >>= 1) v += __shfl_down(v, off);
        acc[e] = v;
    }
    if (lane == 0) {
        float m = acc[0];
#pragma unroll
        for (int e = 1; e < NEXP; e++) m = fmaxf(m, acc[e]);
        float p[NEXP]; float s = 0.f;
#pragma unroll
        for (int e = 0; e < NEXP; e++) { p[e] = __expf(acc[e] - m); s += p[e]; }
        int i0 = 0; float v0 = p[0];
#pragma unroll
        for (int e = 1; e < NEXP; e++) if (p[e] > v0) { v0 = p[e]; i0 = e; }
        int i1 = -1; float v1 = -1.f;
#pragma unroll
        for (int e = 0; e < NEXP; e++) if (e != i0 && p[e] > v1) { v1 = p[e]; i1 = e; }
        float inv = 1.f / s;
        topi[2 * t] = i0; topi[2 * t + 1] = i1;
        topw[2 * t] = v0 * inv; topw[2 * t + 1] = v1 * inv;
        atomicAdd(&misc[i0], 1);
        atomicAdd(&misc[i1], 1);
    }
}

__global__ void scan_kernel(int* misc) {
    int* counts = misc;
    int* base   = misc + 32;
    int* te     = misc + 48;
    int* tr     = misc + 128;
    int b = 0, tt = 0;
    for (int e = 0; e < NEXP; e++) {
        int c = counts[e];
        int nt = (c + BM - 1) >> 7;
        base[e] = b;
        for (int i = 0; i < nt; i++) { te[tt] = e; tr[tt] = b + i * BM; tt++; }
        b += nt * BM;
    }
    for (int i = tt; i < MAXMT; i++) te[i] = -1;
}

__global__ void scatter_kernel(const int* __restrict__ topi, const float* __restrict__ topw,
                               int* __restrict__ misc, int* __restrict__ perm,
                               float* __restrict__ pw) {
    int t = blockIdx.x * 256 + threadIdx.x;
    if (t >= TTOK) return;
    int* fill = misc + 16;
    int* base = misc + 32;
#pragma unroll
    for (int k = 0; k < 2; k++) {
        int e = topi[2 * t + k];
        int pos = base[e] + atomicAdd(&fill[e], 1);
        perm[pos] = t;
        pw[pos] = topw[2 * t + k];
    }
}

// ---------------- GEMM kernels (bf16, gll16, BK=64) ----------------
// C[M,N] = A[M,K] @ B[N,K]^T. R8 fused skeleton with BK 32->64: halves barrier
// count, doubles MFMA per K-step (R9 post-mortem: time ~ K-steps x drain, so
// MFMA-per-barrier is the lever, not occupancy).
// LDS tiles [128][64] bf16 (16 KB each). Staging: 4 gll16/wave/tile; inst i
// covers rows wid*32+8i..+8; lane l -> row +(l>>3), PRE-SWIZZLED global chunk
// ((l&7)^(l>>3))*16B; LDS dest linear (HW: base + lane*16B).
// Read side: frag chunk cc = kg + 4*t (t = k-subtile 0/1) read at cc^(row&7)
// where row&7 == col&7 for frag rows -> involution matches store key (rule #21).
// Banks: 16 lanes over 8 4-bank slots, 2-way = free (m136).
// XCD-chunked jn-major 1D grid (T1).
// NOTE: h13 (256,2) REQUIRED (dual acc; (256,4) spilled in R5). out (256,3).

template<bool GROUPED>
__global__ __launch_bounds__(256, 2) void gemm_h13_k(
    const u16* __restrict__ Xb,
    const u16* __restrict__ W1b, const u16* __restrict__ W3b,
    u16* __restrict__ H,
    const int* __restrict__ perm,
    const int* __restrict__ te, const int* __restrict__ tr,
    const u16* __restrict__ zrow,
    int N, int K, int nt_m, int chunk)
{
    const int q = (blockIdx.x & 7) * chunk + (blockIdx.x >> 3);
    if (q >= nt_m * (N / BN)) return;
    const int jn = q / nt_m, im = q % nt_m;
    int e, slot0;
    if (GROUPED) { e = te[im]; if (e < 0) return; slot0 = tr[im]; }
    else         { e = 0; slot0 = im * BM; }
    const int n0 = jn * BN;
    const u16* W1 = W1b + (size_t)e * N * K;
    const u16* W3 = W3b + (size_t)e * N * K;

    __shared__ __align__(16) u16 As[BM * BK];
    __shared__ __align__(16) u16 B1s[BM * BK];
    __shared__ __align__(16) u16 B3s[BM * BK];

    const int tid = threadIdx.x;
    const int lane = tid & 63, wid = tid >> 6;
    const int wr = wid >> 1, wc = wid & 1;
    const int col = lane & 15, kg = lane >> 4;

    // staging: lane l -> row-in-group l>>3, pre-swz global chunk (l&7)^(l>>3)
    const int lr8 = lane >> 3;
    const int kb  = ((lane & 7) ^ lr8) * 8;          // u16 elems
    const int rB0 = wid * 32 + lr8;                  // base row (inst i adds 8i)
    const u16* gA[4];
#pragma unroll
    for (int i = 0; i < 4; i++) {
        if (GROUPED) {
            int ta = perm[slot0 + rB0 + 8 * i];
            gA[i] = (ta >= 0 ? Xb + (size_t)ta * K : zrow) + kb;
        } else {
            gA[i] = Xb + (size_t)(slot0 + rB0 + 8 * i) * K + kb;
        }
    }
    const u16* g1 = W1 + (size_t)(n0 + rB0) * K + kb;
    const u16* g3 = W3 + (size_t)(n0 + rB0) * K + kb;

    const int ldsI = (wid * 32) * BK;                // u16 offset of inst 0
    const int swr = col & 7;                         // read-side swizzle key

    f32x4 acc1[4][4] = {};
    f32x4 acc3[4][4] = {};

    for (int k0 = 0; k0 < K; k0 += BK) {
#pragma unroll
        for (int i = 0; i < 4; i++) {
            gll16(gA[i] + k0, As + ldsI + i * 8 * BK);
            gll16(g1 + (size_t)(8 * i) * K + k0, B1s + ldsI + i * 8 * BK);
            gll16(g3 + (size_t)(8 * i) * K + k0, B3s + ldsI + i * 8 * BK);
        }
        __syncthreads();

        short8 a[4][2];
#pragma unroll
        for (int mi = 0; mi < 4; mi++)
#pragma unroll
            for (int t = 0; t < 2; t++) {
                int cc = kg + 4 * t;
                a[mi][t] = *(const short8*)(As + (wr * 64 + mi * 16 + col) * BK + ((cc ^ swr) * 8));
            }
#pragma unroll
        for (int t = 0; t < 2; t++) {
#pragma unroll
            for (int ni = 0; ni < 4; ni++) {
                int cc = kg + 4 * t;
                int off = (wc * 64 + ni * 16 + col) * BK + ((cc ^ swr) * 8);
                short8 v1 = *(const short8*)(B1s + off);
                short8 v3 = *(const short8*)(B3s + off);
#pragma unroll
                for (int mi = 0; mi < 4; mi++) {
                    acc1[mi][ni] = __builtin_amdgcn_mfma_f32_16x16x32_bf16(a[mi][t], v1, acc1[mi][ni], 0, 0, 0);
                    acc3[mi][ni] = __builtin_amdgcn_mfma_f32_16x16x32_bf16(a[mi][t], v3, acc3[mi][ni], 0, 0, 0);
                }
            }
        }
        __syncthreads();
    }

    // epilogue: h = silu(acc1) * acc3, store bf16 (padding rows produce 0)
#pragma unroll
    for (int mi = 0; mi < 4; mi++) {
#pragma unroll
        for (int j = 0; j < 4; j++) {
            int row = slot0 + wr * 64 + mi * 16 + kg * 4 + j;
#pragma unroll
            for (int ni = 0; ni < 4; ni++) {
                float v1 = acc1[mi][ni][j];
                float v3 = acc3[mi][ni][j];
                float hv = v1 / (1.f + __expf(-v1)) * v3;
                int c = n0 + wc * 64 + ni * 16 + col;
                H[(size_t)row * N + c] = f2bf(hv);
            }
        }
    }
}

template<bool ATOMIC>
__global__ __launch_bounds__(256, 3) void gemm_out_k(
    const u16* __restrict__ Hm,
    const u16* __restrict__ W2b,
    float* __restrict__ Out,
    const int* __restrict__ perm, const float* __restrict__ pw,
    const int* __restrict__ te, const int* __restrict__ tr,
    int K, int nt_m, int chunk)
{
    const int q = (blockIdx.x & 7) * chunk + (blockIdx.x >> 3);
    if (q >= nt_m * (DIM_ / BN)) return;
    const int jn = q / nt_m, im = q % nt_m;
    int e, slot0;
    if (ATOMIC) { e = te[im]; if (e < 0) return; slot0 = tr[im]; }
    else        { e = 0; slot0 = im * BM; }
    const int n0 = jn * BN;
    const u16* W2 = W2b + (size_t)e * DIM_ * K;

    __shared__ __align__(16) u16 As[BM * BK];
    __shared__ __align__(16) u16 Bs[BM * BK];

    const int tid = threadIdx.x;
    const int lane = tid & 63, wid = tid >> 6;
    const int wr = wid >> 1, wc = wid & 1;
    const int col = lane & 15, kg = lane >> 4;

    const int lr8 = lane >> 3;
    const int kb  = ((lane & 7) ^ lr8) * 8;
    const int rB0 = wid * 32 + lr8;
    const u16* gA = Hm + (size_t)(slot0 + rB0) * K + kb;
    const u16* gB = W2 + (size_t)(n0 + rB0) * K + kb;
    const int ldsI = (wid * 32) * BK;
    const int swr = col & 7;

    f32x4 acc[4][4] = {};

    for (int k0 = 0; k0 < K; k0 += BK) {
#pragma unroll
        for (int i = 0; i < 4; i++) {
            gll16(gA + (size_t)(8 * i) * K + k0, As + ldsI + i * 8 * BK);
            gll16(gB + (size_t)(8 * i) * K + k0, Bs + ldsI + i * 8 * BK);
        }
        __syncthreads();

        short8 a[4][2];
#pragma unroll
        for (int mi = 0; mi < 4; mi++)
#pragma unroll
            for (int t = 0; t < 2; t++) {
                int cc = kg + 4 * t;
                a[mi][t] = *(const short8*)(As + (wr * 64 + mi * 16 + col) * BK + ((cc ^ swr) * 8));
            }
#pragma unroll
        for (int t = 0; t < 2; t++) {
#pragma unroll
            for (int ni = 0; ni < 4; ni++) {
                int cc = kg + 4 * t;
                int off = (wc * 64 + ni * 16 + col) * BK + ((cc ^ swr) * 8);
                short8 bv = *(const short8*)(Bs + off);
#pragma unroll
                for (int mi = 0; mi < 4; mi++)
                    acc[mi][ni] = __builtin_amdgcn_mfma_f32_16x16x32_bf16(a[mi][t], bv, acc[mi][ni], 0, 0, 0);
            }
        }
        __syncthreads();
    }

#pragma unroll
    for (int mi = 0; mi < 4; mi++) {
#pragma unroll
        for (int j = 0; j < 4; j++) {
            int rloc = wr * 64 + mi * 16 + kg * 4 + j;
            int slot = slot0 + rloc;
            if (ATOMIC) {
                int token = perm[slot];
                if (token < 0) continue;
                float w = pw[slot];
#pragma unroll
                for (int ni = 0; ni < 4; ni++) {
                    int c = n0 + wc * 64 + ni * 16 + col;
                    atomicAdd(&Out[(size_t)token * DIM_ + c], acc[mi][ni][j] * w);
                }
            } else {
#pragma unroll
                for (int ni = 0; ni < 4; ni++) {
                    int c = n0 + wc * 64 + ni * 16 + col;
                    Out[(size_t)slot * DIM_ + c] = acc[mi][ni][j];
                }
            }
        }
    }
}

// ---------------- launch ----------------

extern "C" void kernel_launch(void* const* d_in, const int* in_sizes, int n_in,
                              void* d_out, int out_size, void* d_ws, size_t ws_size,
                              hipStream_t stream) {
    (void)in_sizes; (void)n_in; (void)out_size; (void)ws_size;
    const float* x   = (const float*)d_in[0];
    const float* gw  = (const float*)d_in[1];
    const float* w1  = (const float*)d_in[2];
    const float* w2  = (const float*)d_in[3];
    const float* w3  = (const float*)d_in[4];
    const float* sw1 = (const float*)d_in[5];
    const float* sw2 = (const float*)d_in[6];
    const float* sw3 = (const float*)d_in[7];
    float* out = (float*)d_out;

    char* ws = (char*)d_ws;
    size_t off = 0;
    auto take = [&](size_t bytes) -> void* {
        void* p = ws + off;
        off += (bytes + 255) & ~(size_t)255;
        return p;
    };
    const size_t nHB = ((size_t)MAXROWS * INTER_ > (size_t)TTOK * SINTER_)
                       ? (size_t)MAXROWS * INTER_ : (size_t)TTOK * SINTER_;
    u16*   xb      = (u16*)take((size_t)TTOK * DIM_ * 2);
    u16*   hbuf    = (u16*)take(nHB * 2);
    int*   perm_rt = (int*)take((size_t)MAXROWS * 4);
    float* pw_rt   = (float*)take((size_t)MAXROWS * 4);
    int*   topi    = (int*)take((size_t)TTOK * 2 * 4);
    float* topw    = (float*)take((size_t)TTOK * 2 * 4);
    int*   misc    = (int*)take(1024);
    int*   zrow    = (int*)take(4096);
    const size_t nW  = (size_t)NEXP * INTER_ * DIM_;     // w1 / w2 / w3 each
    const size_t nSW = (size_t)SINTER_ * DIM_;           // sw1 / sw2 / sw3 each
    u16* w1b  = (u16*)take(nW * 2);
    u16* w2b  = (u16*)take(nW * 2);
    u16* w3b  = (u16*)take(nW * 2);
    u16* sw1b = (u16*)take(nSW * 2);
    u16* sw2b = (u16*)take(nSW * 2);
    u16* sw3b = (u16*)take(nSW * 2);

    init_kernel<<<MAXROWS / 256, 256, 0, stream>>>(perm_rt, pw_rt, misc, zrow);
    cvt_kernel<<<2048, 256, 0, stream>>>(x, xb, TTOK * DIM_ / 8);
    gate_kernel<<<TTOK, 64, 0, stream>>>(x, gw, topi, topw, misc);
    scan_kernel<<<1, 1, 0, stream>>>(misc);
    scatter_kernel<<<TTOK / 256, 256, 0, stream>>>(topi, topw, misc, perm_rt, pw_rt);

    // weight conversion passes (HBM-bound)
    cvt_kernel<<<4096, 256, 0, stream>>>(w1,  w1b,  (int)(nW / 8));
    cvt_kernel<<<4096, 256, 0, stream>>>(w2,  w2b,  (int)(nW / 8));
    cvt_kernel<<<4096, 256, 0, stream>>>(w3,  w3b,  (int)(nW / 8));
    cvt_kernel<<<4096, 256, 0, stream>>>(sw1, sw1b, (int)(nSW / 8));
    cvt_kernel<<<4096, 256, 0, stream>>>(sw2, sw2b, (int)(nSW / 8));
    cvt_kernel<<<4096, 256, 0, stream>>>(sw3, sw3b, (int)(nSW / 8));

    auto grid8 = [](int total) { return ((total + 7) / 8) * 8; };
    auto chunk8 = [](int total) { return (total + 7) / 8; };

    const int ntm_sh = TTOK / BM;   // 32

    // shared expert
    {
        int total = ntm_sh * (SINTER_ / BN);
        gemm_h13_k<false><<<grid8(total), 256, 0, stream>>>(
            xb, sw1b, sw3b, hbuf, nullptr, nullptr, nullptr, (const u16*)zrow,
            SINTER_, DIM_, ntm_sh, chunk8(total));
    }
    {
        int total = ntm_sh * (DIM_ / BN);
        gemm_out_k<false><<<grid8(total), 256, 0, stream>>>(
            hbuf, sw2b, out, nullptr, nullptr, nullptr, nullptr,
            SINTER_, ntm_sh, chunk8(total));
    }
    // routed experts
    {
        int total = MAXMT * (INTER_ / BN);
        gemm_h13_k<true><<<grid8(total), 256, 0, stream>>>(
            xb, w1b, w3b, hbuf, perm_rt, misc + 48, misc + 128, (const u16*)zrow,
            INTER_, DIM_, MAXMT, chunk8(total));
    }
    {
        int total = MAXMT * (DIM_ / BN);
        gemm_out_k<true><<<grid8(total), 256, 0, stream>>>(
            hbuf, w2b, out, perm_rt, pw_rt, misc + 48, misc + 128,
            INTER_, MAXMT, chunk8(total));
    }
}